// Round 1
// baseline (39.799 us; speedup 1.0000x reference)
//
#include <hip/hip_runtime.h>
#include <math.h>

#define HALF_LOG_2PI_F 0.9189385332046727f

// ---------------------------------------------------------------------------
// Kernel 1 (prep, single block): compute per-feature quadratic coefficients.
//   means = tanh(rp[:D]) * 2
//   stds  = softplus(rp[D:]) + 1e-6
//   deg[k] from edges (endpoint multiplicity)
//   A[k] = deg * (-0.5 / s^2)
//   B[k] = deg * (m / s^2)
//   Csum = sum_k deg * (-0.5*m^2/s^2 - log(s) - HALF_LOG_2PI)
// ---------------------------------------------------------------------------
__global__ void clt_prep_kernel(const float* __restrict__ rp,
                                const int* __restrict__ edges,
                                float* __restrict__ A,
                                float* __restrict__ B,
                                float* __restrict__ csum,
                                int D, int E) {
    extern __shared__ float sdeg[];   // D floats
    for (int k = threadIdx.x; k < D; k += blockDim.x) sdeg[k] = 0.0f;
    __syncthreads();
    for (int e = threadIdx.x; e < E; e += blockDim.x) {
        int i = edges[2 * e];
        int j = edges[2 * e + 1];
        // integer-valued float adds: exact, order-independent -> deterministic
        atomicAdd(&sdeg[i], 1.0f);
        atomicAdd(&sdeg[j], 1.0f);
    }
    __syncthreads();

    float local_c = 0.0f;
    for (int k = threadIdx.x; k < D; k += blockDim.x) {
        float m = tanhf(rp[k]) * 2.0f;
        float sx = rp[D + k];
        // numerically-stable softplus: max(x,0) + log1p(exp(-|x|))
        float s = fmaxf(sx, 0.0f) + log1pf(expf(-fabsf(sx))) + 1e-6f;
        float inv_s2 = 1.0f / (s * s);
        float deg = sdeg[k];
        A[k] = deg * (-0.5f * inv_s2);
        B[k] = deg * (m * inv_s2);
        local_c += deg * (-0.5f * m * m * inv_s2 - logf(s) - HALF_LOG_2PI_F);
    }

    // deterministic block reduction of local_c
    __shared__ float wsum[16];
    for (int off = 32; off > 0; off >>= 1)
        local_c += __shfl_down(local_c, off, 64);
    int wid = threadIdx.x >> 6;
    int lane = threadIdx.x & 63;
    if (lane == 0) wsum[wid] = local_c;
    __syncthreads();
    if (threadIdx.x == 0) {
        float t = 0.0f;
        int nw = (blockDim.x + 63) >> 6;
        for (int w = 0; w < nw; ++w) t += wsum[w];
        *csum = t;
    }
}

// ---------------------------------------------------------------------------
// Kernel 2 (main): one 256-thread block per row.
//   out[row] = sum_k x*fma(A,x,B) + Csum
// float4 coalesced loads; A/B are 16 KB total -> L1/L2 resident across rows.
// ---------------------------------------------------------------------------
__global__ __launch_bounds__(256) void clt_row_kernel(
        const float* __restrict__ x,
        const float* __restrict__ A,
        const float* __restrict__ B,
        const float* __restrict__ csum,
        float* __restrict__ out,
        int D) {
    const int row = blockIdx.x;
    const float4* xv = (const float4*)(x + (size_t)row * (size_t)D);
    const float4* Av = (const float4*)A;
    const float4* Bv = (const float4*)B;
    const int nv = D >> 2;

    float acc = 0.0f;
    for (int i = threadIdx.x; i < nv; i += blockDim.x) {
        float4 xq = xv[i];
        float4 aq = Av[i];
        float4 bq = Bv[i];
        acc += xq.x * fmaf(aq.x, xq.x, bq.x);
        acc += xq.y * fmaf(aq.y, xq.y, bq.y);
        acc += xq.z * fmaf(aq.z, xq.z, bq.z);
        acc += xq.w * fmaf(aq.w, xq.w, bq.w);
    }
    // scalar tail (D not multiple of 4) — no-op for D=2048
    for (int k = (nv << 2) + threadIdx.x; k < D; k += blockDim.x) {
        float xs = x[(size_t)row * (size_t)D + k];
        acc += xs * fmaf(A[k], xs, B[k]);
    }

    // deterministic reduction: wave shuffle then fixed-order LDS sum
    for (int off = 32; off > 0; off >>= 1)
        acc += __shfl_down(acc, off, 64);
    __shared__ float wsum[4];
    int wid = threadIdx.x >> 6;
    int lane = threadIdx.x & 63;
    if (lane == 0) wsum[wid] = acc;
    __syncthreads();
    if (threadIdx.x == 0) {
        out[row] = wsum[0] + wsum[1] + wsum[2] + wsum[3] + *csum;
    }
}

extern "C" void kernel_launch(void* const* d_in, const int* in_sizes, int n_in,
                              void* d_out, int out_size, void* d_ws, size_t ws_size,
                              hipStream_t stream) {
    const float* x     = (const float*)d_in[0];
    const float* rp    = (const float*)d_in[1];
    const int*   edges = (const int*)d_in[2];
    float* out = (float*)d_out;

    const int D = in_sizes[1] / 2;       // 2048
    const int E = in_sizes[2] / 2;       // D-1
    const int N = out_size;              // 16384 rows

    float* A    = (float*)d_ws;          // [D]
    float* B    = A + D;                 // [D]
    float* csum = B + D;                 // [1]

    clt_prep_kernel<<<1, 256, D * sizeof(float), stream>>>(rp, edges, A, B, csum, D, E);
    clt_row_kernel<<<N, 256, 0, stream>>>(x, A, B, csum, out, D);
}

// Round 2
// 35.601 us; speedup vs baseline: 1.1179x; 1.1179x over previous
//
#include <hip/hip_runtime.h>
#include <math.h>

#define HALF_LOG_2PI_F 0.9189385332046727f

// ---------------------------------------------------------------------------
// Kernel 1 (prep, single block of 1024): per-feature quadratic coefficients.
//   A[k] = deg * (-0.5 / s^2)
//   B[k] = deg * (m / s^2)
//   Csum = sum_k deg * (-0.5*m^2/s^2 - log(s) - HALF_LOG_2PI)
// ---------------------------------------------------------------------------
__global__ void clt_prep_kernel(const float* __restrict__ rp,
                                const int* __restrict__ edges,
                                float* __restrict__ A,
                                float* __restrict__ B,
                                float* __restrict__ csum,
                                int D, int E) {
    extern __shared__ float sdeg[];   // D floats
    for (int k = threadIdx.x; k < D; k += blockDim.x) sdeg[k] = 0.0f;
    __syncthreads();
    for (int e = threadIdx.x; e < E; e += blockDim.x) {
        int i = edges[2 * e];
        int j = edges[2 * e + 1];
        // integer-valued float adds: exact, order-independent -> deterministic
        atomicAdd(&sdeg[i], 1.0f);
        atomicAdd(&sdeg[j], 1.0f);
    }
    __syncthreads();

    float local_c = 0.0f;
    for (int k = threadIdx.x; k < D; k += blockDim.x) {
        float m = tanhf(rp[k]) * 2.0f;
        float sx = rp[D + k];
        // numerically-stable softplus: max(x,0) + log1p(exp(-|x|))
        float s = fmaxf(sx, 0.0f) + log1pf(expf(-fabsf(sx))) + 1e-6f;
        float inv_s2 = 1.0f / (s * s);
        float deg = sdeg[k];
        A[k] = deg * (-0.5f * inv_s2);
        B[k] = deg * (m * inv_s2);
        local_c += deg * (-0.5f * m * m * inv_s2 - logf(s) - HALF_LOG_2PI_F);
    }

    // deterministic block reduction of local_c
    __shared__ float wsum[16];
    for (int off = 32; off > 0; off >>= 1)
        local_c += __shfl_down(local_c, off, 64);
    int wid = threadIdx.x >> 6;
    int lane = threadIdx.x & 63;
    if (lane == 0) wsum[wid] = local_c;
    __syncthreads();
    if (threadIdx.x == 0) {
        float t = 0.0f;
        int nw = (blockDim.x + 63) >> 6;
        for (int w = 0; w < nw; ++w) t += wsum[w];
        *csum = t;
    }
}

// ---------------------------------------------------------------------------
// Kernel 2 (main, fast path): ONE WAVE PER ROW, grid-strided.
//   - A/B float4 fragments loaded once per wave into registers (NI*2 float4),
//     reused across all grid-strided rows.
//   - Per row: NI coalesced float4 x-loads per lane, FMA dot, 6-shuffle
//     wave reduction. No LDS, no __syncthreads.
//   NI = D / 256  (D must be a multiple of 256 for this path).
// ---------------------------------------------------------------------------
template <int NI>
__global__ __launch_bounds__(256) void clt_rows_fast(
        const float* __restrict__ x,
        const float* __restrict__ A,
        const float* __restrict__ B,
        const float* __restrict__ csum,
        float* __restrict__ out,
        int D, int N, int total_waves) {
    const int lane = threadIdx.x & 63;
    const int gwave = blockIdx.x * (blockDim.x >> 6) + (threadIdx.x >> 6);

    const float4* Av = (const float4*)A;
    const float4* Bv = (const float4*)B;
    float4 a4[NI], b4[NI];
#pragma unroll
    for (int i = 0; i < NI; ++i) {
        a4[i] = Av[i * 64 + lane];
        b4[i] = Bv[i * 64 + lane];
    }
    const float c = *csum;

    for (int r = gwave; r < N; r += total_waves) {
        const float4* xv = (const float4*)(x + (size_t)r * (size_t)D);
        float acc0 = 0.0f, acc1 = 0.0f;
#pragma unroll
        for (int i = 0; i < NI; ++i) {
            float4 xq = xv[i * 64 + lane];
            acc0 += xq.x * fmaf(a4[i].x, xq.x, b4[i].x);
            acc1 += xq.y * fmaf(a4[i].y, xq.y, b4[i].y);
            acc0 += xq.z * fmaf(a4[i].z, xq.z, b4[i].z);
            acc1 += xq.w * fmaf(a4[i].w, xq.w, b4[i].w);
        }
        float acc = acc0 + acc1;
#pragma unroll
        for (int off = 32; off > 0; off >>= 1)
            acc += __shfl_down(acc, off, 64);
        if (lane == 0) out[r] = acc + c;
    }
}

// Generic fallback (any D): block-per-row, as in R1.
__global__ __launch_bounds__(256) void clt_row_generic(
        const float* __restrict__ x,
        const float* __restrict__ A,
        const float* __restrict__ B,
        const float* __restrict__ csum,
        float* __restrict__ out,
        int D) {
    const int row = blockIdx.x;
    float acc = 0.0f;
    for (int k = threadIdx.x; k < D; k += blockDim.x) {
        float xs = x[(size_t)row * (size_t)D + k];
        acc += xs * fmaf(A[k], xs, B[k]);
    }
    for (int off = 32; off > 0; off >>= 1)
        acc += __shfl_down(acc, off, 64);
    __shared__ float wsum[4];
    int wid = threadIdx.x >> 6;
    int lane = threadIdx.x & 63;
    if (lane == 0) wsum[wid] = acc;
    __syncthreads();
    if (threadIdx.x == 0)
        out[row] = wsum[0] + wsum[1] + wsum[2] + wsum[3] + *csum;
}

extern "C" void kernel_launch(void* const* d_in, const int* in_sizes, int n_in,
                              void* d_out, int out_size, void* d_ws, size_t ws_size,
                              hipStream_t stream) {
    const float* x     = (const float*)d_in[0];
    const float* rp    = (const float*)d_in[1];
    const int*   edges = (const int*)d_in[2];
    float* out = (float*)d_out;

    const int D = in_sizes[1] / 2;       // 2048
    const int E = in_sizes[2] / 2;       // D-1
    const int N = out_size;              // 16384 rows

    float* A    = (float*)d_ws;          // [D]
    float* B    = A + D;                 // [D]
    float* csum = B + D;                 // [1]

    clt_prep_kernel<<<1, 1024, D * sizeof(float), stream>>>(rp, edges, A, B, csum, D, E);

    const int NI = D / 256;
    if (D % 256 == 0 && (NI == 2 || NI == 4 || NI == 8 || NI == 16)) {
        // target ~4 rows per wave
        int waves = (N + 3) / 4;
        int blocks = (waves + 3) / 4;
        if (blocks < 64) blocks = 64;
        if (blocks > 4096) blocks = 4096;
        int total_waves = blocks * 4;
        switch (NI) {
            case 2:  clt_rows_fast<2><<<blocks, 256, 0, stream>>>(x, A, B, csum, out, D, N, total_waves); break;
            case 4:  clt_rows_fast<4><<<blocks, 256, 0, stream>>>(x, A, B, csum, out, D, N, total_waves); break;
            case 8:  clt_rows_fast<8><<<blocks, 256, 0, stream>>>(x, A, B, csum, out, D, N, total_waves); break;
            default: clt_rows_fast<16><<<blocks, 256, 0, stream>>>(x, A, B, csum, out, D, N, total_waves); break;
        }
    } else {
        clt_row_generic<<<N, 256, 0, stream>>>(x, A, B, csum, out, D);
    }
}